// Round 2
// baseline (2004.992 us; speedup 1.0000x reference)
//
#include <hip/hip_runtime.h>
#include <hip/hip_bf16.h>

// Problem constants (B=2, S=2048, D=512, H=8, hd=64)
constexpr int Bc = 2, Sc = 2048, Dc = 512, Hc = 8, HDc = 64;
constexpr float NEGC = 10000.0f;
constexpr float SCALEC = 0.125f; // 1/sqrt(64)

// ---------------------------------------------------------------------------
// GEMM: Y[M,512] = relu(X[M,512] @ W[512,512] + bias), all f32.
// blockIdx.z selects (W,b,Y) so one launch does Q,K,V.
// 64x64 tile, 256 threads, 4x4 microtile.
// ---------------------------------------------------------------------------
__global__ __launch_bounds__(256)
void gemm_relu(const float* __restrict__ X,
               const float* __restrict__ W0, const float* __restrict__ W1,
               const float* __restrict__ W2,
               const float* __restrict__ b0, const float* __restrict__ b1,
               const float* __restrict__ b2,
               float* __restrict__ Y0, float* __restrict__ Y1,
               float* __restrict__ Y2)
{
    constexpr int N = 512, K = 512;
    __shared__ float As[16][68];   // [k][m], padded stride 68 (16B-aligned)
    __shared__ float Bs[16][64];   // [k][n]

    const int z = blockIdx.z;
    const float* Wp = (z == 0) ? W0 : (z == 1) ? W1 : W2;
    const float* bp = (z == 0) ? b0 : (z == 1) ? b1 : b2;
    float* Yp       = (z == 0) ? Y0 : (z == 1) ? Y1 : Y2;

    const int t  = threadIdx.x;
    const int tx = t & 15, ty = t >> 4;
    const int bm = blockIdx.y * 64, bn = blockIdx.x * 64;

    const int ar = t >> 2;            // A: row within tile (0..63)
    const int ak = (t & 3) * 4;       // A: k offset (0,4,8,12)
    const int bk = t >> 4;            // B: k within tile (0..15)
    const int bc = (t & 15) * 4;      // B: col offset

    float acc[4][4] = {};

    for (int k0 = 0; k0 < K; k0 += 16) {
        const float4 xa = *(const float4*)(X  + (size_t)(bm + ar) * K + k0 + ak);
        const float4 wb = *(const float4*)(Wp + (size_t)(k0 + bk) * N + bn + bc);
        __syncthreads();   // protect LDS from previous iter's readers
        As[ak + 0][ar] = xa.x;
        As[ak + 1][ar] = xa.y;
        As[ak + 2][ar] = xa.z;
        As[ak + 3][ar] = xa.w;
        *(float4*)&Bs[bk][bc] = wb;
        __syncthreads();
        #pragma unroll
        for (int kk = 0; kk < 16; ++kk) {
            const float4 a = *(const float4*)&As[kk][ty * 4];
            const float4 b = *(const float4*)&Bs[kk][tx * 4];
            const float av[4] = {a.x, a.y, a.z, a.w};
            const float bv[4] = {b.x, b.y, b.z, b.w};
            #pragma unroll
            for (int i = 0; i < 4; ++i)
                #pragma unroll
                for (int j = 0; j < 4; ++j)
                    acc[i][j] += av[i] * bv[j];
        }
    }

    float bias[4];
    #pragma unroll
    for (int j = 0; j < 4; ++j) bias[j] = bp[bn + tx * 4 + j];

    #pragma unroll
    for (int i = 0; i < 4; ++i) {
        const size_t row = (size_t)(bm + ty * 4 + i);
        float v[4];
        #pragma unroll
        for (int j = 0; j < 4; ++j) v[j] = fmaxf(acc[i][j] + bias[j], 0.0f);
        *reinterpret_cast<float4*>(Yp + row * N + bn + tx * 4) =
            make_float4(v[0], v[1], v[2], v[3]);
    }
}

// ---------------------------------------------------------------------------
// Attention: one wave (64 lanes) per block; lane owns q-row (q0+lane) of one
// (b,h). Full q row + accumulator in VGPRs; K/V tiles (32 keys x 64 dims)
// staged in LDS, broadcast-read. Online softmax is lane-local. Reference
// semantics preserved exactly: e = qk/8 - 10000*causal - 10000*(1-mask),
// softmax over ALL 2048 keys (additive mask, not hard mask).
// Writes O in-place over Q (each block touches only its own rows).
// ---------------------------------------------------------------------------
__global__ __launch_bounds__(64)
void attn_fwd(const float* __restrict__ Q, const float* __restrict__ Kb,
              const float* __restrict__ Vb, const int* __restrict__ mask,
              float* __restrict__ O)
{
    __shared__ float Ks[32][64];
    __shared__ float Vs[32][64];

    const int lane = threadIdx.x;
    const int b = blockIdx.z, h = blockIdx.y;
    const int qrow = blockIdx.x * 64 + lane;

    const size_t rowoff = (size_t)(b * Sc + qrow) * Dc + h * HDc;

    float q[64];
    #pragma unroll
    for (int i = 0; i < 16; ++i) {
        const float4 tq = *(const float4*)(Q + rowoff + i * 4);
        q[i*4+0] = tq.x; q[i*4+1] = tq.y; q[i*4+2] = tq.z; q[i*4+3] = tq.w;
    }

    float acc[64] = {};
    float m = -1e30f, l = 0.0f;
    const int* mb = mask + b * Sc;

    for (int j0 = 0; j0 < Sc; j0 += 32) {
        // cooperative K/V tile load: 512 float4 per buffer, 8 per lane
        #pragma unroll
        for (int r = 0; r < 8; ++r) {
            const int idx = r * 64 + lane;
            const int row = idx >> 4;
            const int c   = (idx & 15) * 4;
            const size_t g = (size_t)(b * Sc + j0 + row) * Dc + h * HDc + c;
            *(float4*)&Ks[row][c] = *(const float4*)(Kb + g);
            *(float4*)&Vs[row][c] = *(const float4*)(Vb + g);
        }
        __syncthreads();

        for (int sub = 0; sub < 4; ++sub) {
            const int jb = sub * 8;
            float e[8];
            float tmax = -1e30f;
            #pragma unroll
            for (int jj = 0; jj < 8; ++jj) {
                const int j = j0 + jb + jj;
                float s0 = 0.f, s1 = 0.f, s2 = 0.f, s3 = 0.f;
                #pragma unroll
                for (int d4 = 0; d4 < 16; ++d4) {
                    const float4 k4 = *(const float4*)&Ks[jb + jj][d4 * 4];
                    s0 += q[d4*4+0] * k4.x;
                    s1 += q[d4*4+1] * k4.y;
                    s2 += q[d4*4+2] * k4.z;
                    s3 += q[d4*4+3] * k4.w;
                }
                float ev = ((s0 + s1) + (s2 + s3)) * SCALEC;
                if (j > qrow)    ev -= NEGC;   // causal (history_only)
                if (mb[j] == 0)  ev -= NEGC;   // key padding
                e[jj] = ev;
                tmax = fmaxf(tmax, ev);
            }
            const float mnew = fmaxf(m, tmax);
            const float corr = __expf(m - mnew);
            m = mnew;
            l *= corr;
            #pragma unroll
            for (int d = 0; d < 64; ++d) acc[d] *= corr;
            #pragma unroll
            for (int jj = 0; jj < 8; ++jj) {
                const float p = __expf(e[jj] - m);
                l += p;
                #pragma unroll
                for (int d4 = 0; d4 < 16; ++d4) {
                    const float4 v4 = *(const float4*)&Vs[jb + jj][d4 * 4];
                    acc[d4*4+0] += p * v4.x;
                    acc[d4*4+1] += p * v4.y;
                    acc[d4*4+2] += p * v4.z;
                    acc[d4*4+3] += p * v4.w;
                }
            }
        }
        __syncthreads();
    }

    const float inv = 1.0f / l;
    #pragma unroll
    for (int i = 0; i < 16; ++i) {
        float4 o;
        o.x = acc[i*4+0] * inv;
        o.y = acc[i*4+1] * inv;
        o.z = acc[i*4+2] * inv;
        o.w = acc[i*4+3] * inv;
        *(float4*)(O + rowoff + i * 4) = o;
    }
}

// ---------------------------------------------------------------------------
extern "C" void kernel_launch(void* const* d_in, const int* in_sizes, int n_in,
                              void* d_out, int out_size, void* d_ws, size_t ws_size,
                              hipStream_t stream) {
    const float* x  = (const float*)d_in[0];
    const int* mask = (const int*)d_in[1];
    const float* Wq = (const float*)d_in[2];
    const float* bq = (const float*)d_in[3];
    const float* Wk = (const float*)d_in[4];
    const float* bk = (const float*)d_in[5];
    const float* Wv = (const float*)d_in[6];
    const float* bv = (const float*)d_in[7];
    const float* Wo = (const float*)d_in[8];
    const float* bo = (const float*)d_in[9];
    float* out = (float*)d_out;   // reference output dtype is float32

    constexpr size_t MAT = (size_t)Bc * Sc * Dc;   // 2,097,152 floats = 8 MB
    float* Q = (float*)d_ws;        // also holds attention output O in-place
    float* K = Q + MAT;
    float* V = K + MAT;
    // total workspace use: 24 MB

    dim3 blk(256);
    // QKV projections (+relu), one launch, z = {q,k,v}
    dim3 g1(512 / 64, (Bc * Sc) / 64, 3);
    gemm_relu<<<g1, blk, 0, stream>>>(x, Wq, Wk, Wv, bq, bk, bv, Q, K, V);
    // attention, O overwrites Q
    dim3 g2(Sc / 64, Hc, Bc);
    attn_fwd<<<g2, dim3(64), 0, stream>>>(Q, K, V, mask, Q);
    // output projection (+relu) -> f32 d_out
    dim3 g3(512 / 64, (Bc * Sc) / 64, 1);
    gemm_relu<<<g3, blk, 0, stream>>>(Q, Wo, Wo, Wo, bo, bo, bo,
                                      out, out, out);
}

// Round 3
// 220.604 us; speedup vs baseline: 9.0887x; 9.0887x over previous
//
#include <hip/hip_runtime.h>
#include <hip/hip_bf16.h>

// Problem constants (B=2, S=2048, D=512, H=8, hd=64)
constexpr int Bc = 2, Sc = 2048, Dc = 512, Hc = 8, HDc = 64;
constexpr float NEGC = 10000.0f;
constexpr float SCALEC = 0.125f; // 1/sqrt(64)

typedef __attribute__((ext_vector_type(8))) short  short8;
typedef __attribute__((ext_vector_type(4))) float  f32x4;

static __device__ __forceinline__ short f32_to_bf16_bits(float f) {
    unsigned int u = __builtin_bit_cast(unsigned int, f);
    unsigned int r = u + 0x7FFFu + ((u >> 16) & 1u);   // RNE
    return (short)(r >> 16);
}

// ---------------------------------------------------------------------------
// GEMM: Y[M,512] = relu(X[M,512] @ W[512,512] + bias), f32 VALU compute.
// HEADOUT=true: write bf16 head-major [B][H][S][64] (for attention QKV).
// HEADOUT=false: write f32 row-major [M][512] (final projection).
// blockIdx.z selects (W,b,Y) so one launch does Q,K,V.
// ---------------------------------------------------------------------------
template<bool HEADOUT>
__global__ __launch_bounds__(256)
void gemm_relu(const float* __restrict__ X,
               const float* __restrict__ W0, const float* __restrict__ W1,
               const float* __restrict__ W2,
               const float* __restrict__ b0, const float* __restrict__ b1,
               const float* __restrict__ b2,
               float* __restrict__ Y0,
               __hip_bfloat16* __restrict__ H0, __hip_bfloat16* __restrict__ H1,
               __hip_bfloat16* __restrict__ H2)
{
    constexpr int N = 512, K = 512;
    __shared__ float As[16][68];
    __shared__ float Bs[16][64];

    const int z = blockIdx.z;
    const float* Wp = (z == 0) ? W0 : (z == 1) ? W1 : W2;
    const float* bp = (z == 0) ? b0 : (z == 1) ? b1 : b2;
    __hip_bfloat16* Hp = (z == 0) ? H0 : (z == 1) ? H1 : H2;

    const int t  = threadIdx.x;
    const int tx = t & 15, ty = t >> 4;
    const int bm = blockIdx.y * 64, bn = blockIdx.x * 64;

    const int ar = t >> 2;
    const int ak = (t & 3) * 4;
    const int bk = t >> 4;
    const int bc = (t & 15) * 4;

    float acc[4][4] = {};

    for (int k0 = 0; k0 < K; k0 += 16) {
        const float4 xa = *(const float4*)(X  + (size_t)(bm + ar) * K + k0 + ak);
        const float4 wb = *(const float4*)(Wp + (size_t)(k0 + bk) * N + bn + bc);
        __syncthreads();
        As[ak + 0][ar] = xa.x;
        As[ak + 1][ar] = xa.y;
        As[ak + 2][ar] = xa.z;
        As[ak + 3][ar] = xa.w;
        *(float4*)&Bs[bk][bc] = wb;
        __syncthreads();
        #pragma unroll
        for (int kk = 0; kk < 16; ++kk) {
            const float4 a = *(const float4*)&As[kk][ty * 4];
            const float4 b = *(const float4*)&Bs[kk][tx * 4];
            const float av[4] = {a.x, a.y, a.z, a.w};
            const float bv[4] = {b.x, b.y, b.z, b.w};
            #pragma unroll
            for (int i = 0; i < 4; ++i)
                #pragma unroll
                for (int j = 0; j < 4; ++j)
                    acc[i][j] += av[i] * bv[j];
        }
    }

    float bias[4];
    #pragma unroll
    for (int j = 0; j < 4; ++j) bias[j] = bp[bn + tx * 4 + j];

    #pragma unroll
    for (int i = 0; i < 4; ++i) {
        const int mrow = bm + ty * 4 + i;
        float v[4];
        #pragma unroll
        for (int j = 0; j < 4; ++j) v[j] = fmaxf(acc[i][j] + bias[j], 0.0f);
        if constexpr (HEADOUT) {
            // head-major bf16: [(b*H + h)*S + s]*64 + hd
            const int bb = mrow >> 11, ss = mrow & 2047;
            const int n  = bn + tx * 4;
            const int hh = n >> 6, hd = n & 63;
            union { ushort4 u; short s[4]; } pk;
            #pragma unroll
            for (int j = 0; j < 4; ++j) pk.s[j] = f32_to_bf16_bits(v[j]);
            *reinterpret_cast<ushort4*>(
                Hp + (((size_t)(bb * Hc + hh) * Sc + ss) * HDc + hd)) = pk.u;
        } else {
            *reinterpret_cast<float4*>(Y0 + (size_t)mrow * N + bn + tx * 4) =
                make_float4(v[0], v[1], v[2], v[3]);
        }
    }
}

// ---------------------------------------------------------------------------
// MFMA flash attention. 4 waves/block, each wave owns 16 q-rows of one (b,h).
// Swapped QK^T: S = mfma(K, Q) -> lane holds S[key=k0+4g+r][q=q0+c],
// c=lane&15, g=lane>>4 (C/D layout: col=lane&15, row=(lane>>4)*4+reg).
// P-fragment feeds PV mfma in place (zero-padded to K=32; P and V use the
// same (g, elem)->k placement, so the result is k-mapping-robust).
// Exact causal skip: only when first unmasked key fb <= q0 (tail then
// underflows to 0.0f exactly, matching the f32 numpy reference).
// ---------------------------------------------------------------------------
__global__ __launch_bounds__(256)
void attn_mfma(const short* __restrict__ Qh, const short* __restrict__ Kh,
               const short* __restrict__ Vh, const int* __restrict__ mask,
               float* __restrict__ O)
{
    const int lane = threadIdx.x & 63;
    const int wave = threadIdx.x >> 6;
    const int b = blockIdx.z, h = blockIdx.y;
    const int q0 = (blockIdx.x * 4 + wave) * 16;
    const int c  = lane & 15;
    const int g  = lane >> 4;

    const size_t headoff = (size_t)(b * Hc + h) * Sc * HDc;
    const short* Qp = Qh + headoff;
    const short* Kp = Kh + headoff;
    const short* Vp = Vh + headoff;
    const int* mb = mask + b * Sc;

    // first unmasked key index (wave-uniform)
    int fb = Sc;
    for (int base = 0; base < Sc; base += 64) {
        unsigned long long bal = __ballot(mb[base + lane] != 0);
        if (bal) { fb = base + (__ffsll((unsigned long long)bal) - 1); break; }
    }
    const int kmax = (fb <= q0) ? (q0 + 16) : Sc;

    // Q fragments (held in regs): Q[q0+c][g*8+j (+32)]
    const short8 qf0 = *(const short8*)(Qp + (size_t)(q0 + c) * HDc + g * 8);
    const short8 qf1 = *(const short8*)(Qp + (size_t)(q0 + c) * HDc + 32 + g * 8);

    f32x4 acc[4] = {{0.f,0.f,0.f,0.f},{0.f,0.f,0.f,0.f},
                    {0.f,0.f,0.f,0.f},{0.f,0.f,0.f,0.f}};
    float m = -1e30f, l = 0.0f;

    for (int k0 = 0; k0 < kmax; k0 += 16) {
        const short8 kf0 = *(const short8*)(Kp + (size_t)(k0 + c) * HDc + g * 8);
        const short8 kf1 = *(const short8*)(Kp + (size_t)(k0 + c) * HDc + 32 + g * 8);
        f32x4 s = {0.f, 0.f, 0.f, 0.f};
        s = __builtin_amdgcn_mfma_f32_16x16x32_bf16(kf0, qf0, s, 0, 0, 0);
        s = __builtin_amdgcn_mfma_f32_16x16x32_bf16(kf1, qf1, s, 0, 0, 0);

        const int4 mk = *(const int4*)(mb + k0 + 4 * g);
        const int mki[4] = {mk.x, mk.y, mk.z, mk.w};

        float e[4];
        float tmax = -1e30f;
        #pragma unroll
        for (int r = 0; r < 4; ++r) {
            const int key = k0 + 4 * g + r;
            float ev = s[r] * SCALEC;
            if (key > q0 + c)  ev -= NEGC;   // causal
            if (mki[r] == 0)   ev -= NEGC;   // padding
            e[r] = ev;
            tmax = fmaxf(tmax, ev);
        }
        tmax = fmaxf(tmax, __shfl_xor(tmax, 16));
        tmax = fmaxf(tmax, __shfl_xor(tmax, 32));
        const float mnew = fmaxf(m, tmax);
        const float corr = __expf(m - mnew);
        m = mnew;

        float p[4], ps = 0.f;
        #pragma unroll
        for (int r = 0; r < 4; ++r) { p[r] = __expf(e[r] - mnew); ps += p[r]; }
        l = l * corr + ps;

        // rescale acc: need corr for rows q'=4g+r (held by lane q' in group 0)
        float cq[4];
        #pragma unroll
        for (int r = 0; r < 4; ++r) cq[r] = __shfl(corr, 4 * g + r);
        #pragma unroll
        for (int t = 0; t < 4; ++t)
            #pragma unroll
            for (int r = 0; r < 4; ++r) acc[t][r] *= cq[r];

        // P fragment (A-operand), zero-padded to K=32
        short8 pf = {0,0,0,0,0,0,0,0};
        #pragma unroll
        for (int r = 0; r < 4; ++r) pf[r] = f32_to_bf16_bits(p[r]);

        // PV: 4 d-tiles of 16
        #pragma unroll
        for (int t = 0; t < 4; ++t) {
            short8 vf = {0,0,0,0,0,0,0,0};
            #pragma unroll
            for (int j = 0; j < 4; ++j)
                vf[j] = Vp[(size_t)(k0 + 4 * g + j) * HDc + t * 16 + c];
            acc[t] = __builtin_amdgcn_mfma_f32_16x16x32_bf16(pf, vf, acc[t], 0, 0, 0);
        }
    }

    // final l reduction over groups, then per-row normalize + store
    l = l + __shfl_xor(l, 16);
    l = l + __shfl_xor(l, 32);
    const float linv_col = 1.0f / l;
    float linv[4];
    #pragma unroll
    for (int r = 0; r < 4; ++r) linv[r] = __shfl(linv_col, 4 * g + r);

    #pragma unroll
    for (int t = 0; t < 4; ++t)
        #pragma unroll
        for (int r = 0; r < 4; ++r)
            O[(size_t)(b * Sc + q0 + 4 * g + r) * Dc + h * HDc + t * 16 + c] =
                acc[t][r] * linv[r];
}

// ---------------------------------------------------------------------------
extern "C" void kernel_launch(void* const* d_in, const int* in_sizes, int n_in,
                              void* d_out, int out_size, void* d_ws, size_t ws_size,
                              hipStream_t stream) {
    const float* x  = (const float*)d_in[0];
    const int* mask = (const int*)d_in[1];
    const float* Wq = (const float*)d_in[2];
    const float* bq = (const float*)d_in[3];
    const float* Wk = (const float*)d_in[4];
    const float* bk = (const float*)d_in[5];
    const float* Wv = (const float*)d_in[6];
    const float* bv = (const float*)d_in[7];
    const float* Wo = (const float*)d_in[8];
    const float* bo = (const float*)d_in[9];
    float* out = (float*)d_out;   // reference output dtype is float32

    constexpr size_t HEADMAT = (size_t)Bc * Hc * Sc * HDc;  // 2M elems
    __hip_bfloat16* Qh = (__hip_bfloat16*)d_ws;             // 4 MB
    __hip_bfloat16* Kh = Qh + HEADMAT;                      // 4 MB
    __hip_bfloat16* Vh = Kh + HEADMAT;                      // 4 MB
    float* O = (float*)(Vh + HEADMAT);                      // 8 MB f32
    // total workspace use: 20 MB

    dim3 blk(256);
    // QKV projections (+relu) -> bf16 head-major
    dim3 g1(512 / 64, (Bc * Sc) / 64, 3);
    gemm_relu<true><<<g1, blk, 0, stream>>>(x, Wq, Wk, Wv, bq, bk, bv,
                                            nullptr, Qh, Kh, Vh);
    // MFMA flash attention -> O f32 [B*S][512]
    dim3 g2(Sc / 64, Hc, Bc);
    attn_mfma<<<g2, blk, 0, stream>>>((const short*)Qh, (const short*)Kh,
                                      (const short*)Vh, mask, O);
    // output projection (+relu) -> f32 d_out
    dim3 g3(512 / 64, (Bc * Sc) / 64, 1);
    gemm_relu<false><<<g3, blk, 0, stream>>>(O, Wo, Wo, Wo, bo, bo, bo,
                                             out, nullptr, nullptr, nullptr);
}

// Round 4
// 181.965 us; speedup vs baseline: 11.0186x; 1.2123x over previous
//
#include <hip/hip_runtime.h>
#include <hip/hip_bf16.h>

// Problem constants (B=2, S=2048, D=512, H=8, hd=64)
constexpr int Bc = 2, Sc = 2048, Dc = 512, Hc = 8, HDc = 64;
constexpr float NEGC = 10000.0f;
constexpr float SCALEC = 0.125f; // 1/sqrt(64)
constexpr int Mtot = Bc * Sc;    // 4096
constexpr size_t HEADMAT = (size_t)Bc * Hc * Sc * HDc;  // 2M elems

typedef __attribute__((ext_vector_type(8))) short  short8;
typedef __attribute__((ext_vector_type(4))) float  f32x4;

static __device__ __forceinline__ unsigned short f32_to_bf16_bits(float f) {
    unsigned int u = __builtin_bit_cast(unsigned int, f);
    unsigned int r = u + 0x7FFFu + ((u >> 16) & 1u);   // RNE
    return (unsigned short)(r >> 16);
}

// ---------------------------------------------------------------------------
// x f32 -> bf16 (row-major [M][512] unchanged layout)
// ---------------------------------------------------------------------------
__global__ __launch_bounds__(256)
void convert_x(const float* __restrict__ x, unsigned short* __restrict__ Xb, int n)
{
    const int i = (blockIdx.x * 256 + threadIdx.x) * 4;
    if (i >= n) return;
    const float4 v = *(const float4*)(x + i);
    ushort4 o;
    o.x = f32_to_bf16_bits(v.x);
    o.y = f32_to_bf16_bits(v.y);
    o.z = f32_to_bf16_bits(v.z);
    o.w = f32_to_bf16_bits(v.w);
    *(ushort4*)(Xb + i) = o;
}

// ---------------------------------------------------------------------------
// W [512][512] f32 -> W^T [512][512] bf16, z = {Wq,Wk,Wv,Wo}. 64x64 LDS tile.
// ---------------------------------------------------------------------------
__global__ __launch_bounds__(256)
void transpose_w(const float* __restrict__ W0, const float* __restrict__ W1,
                 const float* __restrict__ W2, const float* __restrict__ W3,
                 unsigned short* __restrict__ Wt)
{
    __shared__ float T[64][65];
    const int z = blockIdx.z;
    const float* Wp = (z == 0) ? W0 : (z == 1) ? W1 : (z == 2) ? W2 : W3;
    unsigned short* Op = Wt + (size_t)z * 512 * 512;

    const int kt = blockIdx.y * 64, nt = blockIdx.x * 64;
    const int t = threadIdx.x;
    const int r  = t >> 2, c4 = (t & 3) * 16;

    #pragma unroll
    for (int i = 0; i < 4; ++i) {
        const float4 v = *(const float4*)(Wp + (size_t)(kt + r) * 512 + nt + c4 + 4 * i);
        T[r][c4 + 4*i + 0] = v.x;
        T[r][c4 + 4*i + 1] = v.y;
        T[r][c4 + 4*i + 2] = v.z;
        T[r][c4 + 4*i + 3] = v.w;
    }
    __syncthreads();

    const int n = t >> 2, k4 = (t & 3) * 16;
    #pragma unroll
    for (int i = 0; i < 4; ++i) {
        ushort4 o;
        o.x = f32_to_bf16_bits(T[k4 + 4*i + 0][n]);
        o.y = f32_to_bf16_bits(T[k4 + 4*i + 1][n]);
        o.z = f32_to_bf16_bits(T[k4 + 4*i + 2][n]);
        o.w = f32_to_bf16_bits(T[k4 + 4*i + 3][n]);
        *(ushort4*)(Op + (size_t)(nt + n) * 512 + kt + k4 + 4 * i) = o;
    }
}

// ---------------------------------------------------------------------------
// bf16 MFMA GEMM: Y[M,512] = relu(X[M,512] @ W + bias), W given as W^T bf16.
// No LDS: A/B fragments loaded directly (L2-resident). Wave computes 16m x 64n.
// mfma(a, b): D[row = a's c-index, laid out (g,r)][col = b's c-index, at lane c]
// (same verified convention as attn_mfma).
// HEADOUT: bf16 head-major [z][B][H][S][64]; else f32 row-major [M][512].
// ---------------------------------------------------------------------------
template<bool HEADOUT>
__global__ __launch_bounds__(256)
void gemm_mfma(const unsigned short* __restrict__ Xb,
               const unsigned short* __restrict__ Wt,
               const float* __restrict__ b0, const float* __restrict__ b1,
               const float* __restrict__ b2,
               unsigned short* __restrict__ Hout,
               float* __restrict__ Yf)
{
    const int lane = threadIdx.x & 63, wave = threadIdx.x >> 6;
    const int c = lane & 15, g = lane >> 4;
    const int z = blockIdx.z;
    const unsigned short* Wp = Wt + (size_t)z * 512 * 512;
    const float* bp = (z == 0) ? b0 : (z == 1) ? b1 : b2;
    const int m0 = blockIdx.y * 64 + wave * 16;
    const int n0 = blockIdx.x * 64;

    const unsigned short* arow = Xb + (size_t)(m0 + c) * 512 + g * 8;
    const unsigned short* brow = Wp + (size_t)(n0 + c) * 512 + g * 8;

    f32x4 acc[4] = {{0.f,0.f,0.f,0.f},{0.f,0.f,0.f,0.f},
                    {0.f,0.f,0.f,0.f},{0.f,0.f,0.f,0.f}};

    #pragma unroll
    for (int k0 = 0; k0 < 512; k0 += 32) {
        const short8 a = *(const short8*)(arow + k0);
        #pragma unroll
        for (int t = 0; t < 4; ++t) {
            const short8 b = *(const short8*)(brow + (size_t)t * 16 * 512 + k0);
            acc[t] = __builtin_amdgcn_mfma_f32_16x16x32_bf16(a, b, acc[t], 0, 0, 0);
        }
    }

    #pragma unroll
    for (int t = 0; t < 4; ++t) {
        const int n = n0 + 16 * t + c;
        const float bias = bp[n];
        #pragma unroll
        for (int r = 0; r < 4; ++r) {
            const float v = fmaxf(acc[t][r] + bias, 0.0f);
            const int m = m0 + 4 * g + r;
            if constexpr (HEADOUT) {
                const int bb = m >> 11, ss = m & 2047;
                const int hh = n >> 6,  hd = n & 63;
                Hout[(size_t)z * HEADMAT +
                     (((size_t)(bb * Hc + hh) * Sc + ss) * HDc + hd)] =
                    f32_to_bf16_bits(v);
            } else {
                Yf[(size_t)m * 512 + n] = v;
            }
        }
    }
}

// ---------------------------------------------------------------------------
// MFMA flash attention (unchanged structure from R3, verified). Output now
// bf16 row-major [M][512] to feed the final MFMA GEMM.
// ---------------------------------------------------------------------------
__global__ __launch_bounds__(256)
void attn_mfma(const short* __restrict__ Qh, const short* __restrict__ Kh,
               const short* __restrict__ Vh, const int* __restrict__ mask,
               unsigned short* __restrict__ Ob)
{
    const int lane = threadIdx.x & 63;
    const int wave = threadIdx.x >> 6;
    const int b = blockIdx.z, h = blockIdx.y;
    const int q0 = (blockIdx.x * 4 + wave) * 16;
    const int c  = lane & 15;
    const int g  = lane >> 4;

    const size_t headoff = (size_t)(b * Hc + h) * Sc * HDc;
    const short* Qp = Qh + headoff;
    const short* Kp = Kh + headoff;
    const short* Vp = Vh + headoff;
    const int* mb = mask + b * Sc;

    // first unmasked key index (wave-uniform)
    int fb = Sc;
    for (int base = 0; base < Sc; base += 64) {
        unsigned long long bal = __ballot(mb[base + lane] != 0);
        if (bal) { fb = base + (__ffsll((unsigned long long)bal) - 1); break; }
    }
    const int kmax = (fb <= q0) ? (q0 + 16) : Sc;

    const short8 qf0 = *(const short8*)(Qp + (size_t)(q0 + c) * HDc + g * 8);
    const short8 qf1 = *(const short8*)(Qp + (size_t)(q0 + c) * HDc + 32 + g * 8);

    f32x4 acc[4] = {{0.f,0.f,0.f,0.f},{0.f,0.f,0.f,0.f},
                    {0.f,0.f,0.f,0.f},{0.f,0.f,0.f,0.f}};
    float m = -1e30f, l = 0.0f;

    for (int k0 = 0; k0 < kmax; k0 += 16) {
        const short8 kf0 = *(const short8*)(Kp + (size_t)(k0 + c) * HDc + g * 8);
        const short8 kf1 = *(const short8*)(Kp + (size_t)(k0 + c) * HDc + 32 + g * 8);
        f32x4 s = {0.f, 0.f, 0.f, 0.f};
        s = __builtin_amdgcn_mfma_f32_16x16x32_bf16(kf0, qf0, s, 0, 0, 0);
        s = __builtin_amdgcn_mfma_f32_16x16x32_bf16(kf1, qf1, s, 0, 0, 0);

        const int4 mk = *(const int4*)(mb + k0 + 4 * g);
        const int mki[4] = {mk.x, mk.y, mk.z, mk.w};

        float e[4];
        float tmax = -1e30f;
        #pragma unroll
        for (int r = 0; r < 4; ++r) {
            const int key = k0 + 4 * g + r;
            float ev = s[r] * SCALEC;
            if (key > q0 + c)  ev -= NEGC;   // causal
            if (mki[r] == 0)   ev -= NEGC;   // padding
            e[r] = ev;
            tmax = fmaxf(tmax, ev);
        }
        tmax = fmaxf(tmax, __shfl_xor(tmax, 16));
        tmax = fmaxf(tmax, __shfl_xor(tmax, 32));
        const float mnew = fmaxf(m, tmax);
        const float corr = __expf(m - mnew);
        m = mnew;

        float p[4], ps = 0.f;
        #pragma unroll
        for (int r = 0; r < 4; ++r) { p[r] = __expf(e[r] - mnew); ps += p[r]; }
        l = l * corr + ps;

        float cq[4];
        #pragma unroll
        for (int r = 0; r < 4; ++r) cq[r] = __shfl(corr, 4 * g + r);
        #pragma unroll
        for (int t = 0; t < 4; ++t)
            #pragma unroll
            for (int r = 0; r < 4; ++r) acc[t][r] *= cq[r];

        short8 pf = {0,0,0,0,0,0,0,0};
        #pragma unroll
        for (int r = 0; r < 4; ++r) pf[r] = (short)f32_to_bf16_bits(p[r]);

        #pragma unroll
        for (int t = 0; t < 4; ++t) {
            short8 vf = {0,0,0,0,0,0,0,0};
            #pragma unroll
            for (int j = 0; j < 4; ++j)
                vf[j] = Vp[(size_t)(k0 + 4 * g + j) * HDc + t * 16 + c];
            acc[t] = __builtin_amdgcn_mfma_f32_16x16x32_bf16(pf, vf, acc[t], 0, 0, 0);
        }
    }

    l = l + __shfl_xor(l, 16);
    l = l + __shfl_xor(l, 32);
    const float linv_col = 1.0f / l;
    float linv[4];
    #pragma unroll
    for (int r = 0; r < 4; ++r) linv[r] = __shfl(linv_col, 4 * g + r);

    #pragma unroll
    for (int t = 0; t < 4; ++t)
        #pragma unroll
        for (int r = 0; r < 4; ++r)
            Ob[(size_t)(b * Sc + q0 + 4 * g + r) * Dc + h * HDc + t * 16 + c] =
                f32_to_bf16_bits(acc[t][r] * linv[r]);
}

// ---------------------------------------------------------------------------
extern "C" void kernel_launch(void* const* d_in, const int* in_sizes, int n_in,
                              void* d_out, int out_size, void* d_ws, size_t ws_size,
                              hipStream_t stream) {
    const float* x  = (const float*)d_in[0];
    const int* mask = (const int*)d_in[1];
    const float* Wq = (const float*)d_in[2];
    const float* bq = (const float*)d_in[3];
    const float* Wk = (const float*)d_in[4];
    const float* bk = (const float*)d_in[5];
    const float* Wv = (const float*)d_in[6];
    const float* bv = (const float*)d_in[7];
    const float* Wo = (const float*)d_in[8];
    const float* bo = (const float*)d_in[9];
    float* out = (float*)d_out;   // reference output dtype is float32

    // workspace layout (ushort elems unless noted):
    unsigned short* Xb = (unsigned short*)d_ws;          // 2M   (4 MB)
    unsigned short* Wt = Xb + (size_t)Mtot * 512;        // 4x256K (2 MB)
    unsigned short* Qh = Wt + (size_t)4 * 512 * 512;     // 2M
    unsigned short* Kh = Qh + HEADMAT;                   // 2M
    unsigned short* Vh = Kh + HEADMAT;                   // 2M
    unsigned short* Ob = Vh + HEADMAT;                   // 2M
    // total: 18 MB

    // 1) x -> bf16
    convert_x<<<dim3((Mtot * 512) / 1024), dim3(256), 0, stream>>>(
        x, Xb, Mtot * 512);
    // 2) W -> W^T bf16 (all four)
    transpose_w<<<dim3(8, 8, 4), dim3(256), 0, stream>>>(Wq, Wk, Wv, Wo, Wt);
    // 3) QKV projections (+relu) -> bf16 head-major
    gemm_mfma<true><<<dim3(8, Mtot / 64, 3), dim3(256), 0, stream>>>(
        Xb, Wt, bq, bk, bv, Qh, nullptr);
    // 4) MFMA flash attention -> bf16 row-major Ob
    attn_mfma<<<dim3(Sc / 64, Hc, Bc), dim3(256), 0, stream>>>(
        (const short*)Qh, (const short*)Kh, (const short*)Vh, mask, Ob);
    // 5) output projection (+relu) -> f32 d_out  (Wo is Wt slot 3)
    gemm_mfma<false><<<dim3(8, Mtot / 64, 1), dim3(256), 0, stream>>>(
        Ob, Wt + (size_t)3 * 512 * 512, bo, bo, bo, nullptr, out);
}